// Round 17
// baseline (38932.031 us; speedup 1.0000x reference)
//
#include <hip/hip_runtime.h>
#include <math.h>

// Problem constants (reference: B,T,D,H = 32,2048,512,512)
#define BB   32
#define TT   2048
#define DD   512
#define HH   512
#define G4H  2048   // 4*H

// ---------------------------------------------------------------------------
// Phase A: xw[t_local*32 + b][col] = sum_d X[b][t0+t][d] * W[d][col] + bias[col]
// fp32 tiled GEMM: 128x128 block tile, 16 K-step, 256 threads, 8x8 microtile.
// At t0==0 also zeroes the 64 wave-slot counters and the hx tag buffer.
// ---------------------------------------------------------------------------
__global__ __launch_bounds__(256, 2) void gemm_xw(
    const float* __restrict__ X, const float* __restrict__ Wm,
    const float* __restrict__ bias, float* __restrict__ xw,
    int t0, unsigned int* __restrict__ ctr, unsigned long long* __restrict__ hx)
{
    if (t0 == 0) {
        if (blockIdx.x == 0 && blockIdx.y == 0 && threadIdx.x < 64)
            ctr[threadIdx.x * 16] = 0u;     // (p,w) counter at (p*8+w)*16
        if (blockIdx.x == 0) {
            const int n = 2 * BB * HH;               // 32768 u64 slots
            const int stride = gridDim.y * 256;
            for (int i = blockIdx.y * 256 + threadIdx.x; i < n; i += stride)
                hx[i] = 0ull;
        }
    }

    __shared__ float As[16][128];
    __shared__ float Bs[16][128];

    const int tid  = threadIdx.x;
    const int row0 = blockIdx.y * 128;   // rows: (t_local, b) t-major
    const int col0 = blockIdx.x * 128;
    const int tx = tid & 15;
    const int ty = tid >> 4;

    float acc[8][8];
    #pragma unroll
    for (int i = 0; i < 8; ++i)
        #pragma unroll
        for (int j = 0; j < 8; ++j) acc[i][j] = 0.f;

    for (int k0 = 0; k0 < DD; k0 += 16) {
        #pragma unroll
        for (int i = 0; i < 2; ++i) {
            int qa = tid + i * 256;          // 0..511 quads
            int r  = qa >> 2, kq = qa & 3;
            int grow = row0 + r;
            int b = grow & 31, tl = grow >> 5;
            const float4 a = *(const float4*)(X + ((size_t)b * TT + t0 + tl) * DD + k0 + kq * 4);
            As[kq*4+0][r] = a.x; As[kq*4+1][r] = a.y;
            As[kq*4+2][r] = a.z; As[kq*4+3][r] = a.w;

            int qb = tid + i * 256;
            int kb = qb >> 5, c4 = qb & 31;
            *(float4*)&Bs[kb][c4*4] =
                *(const float4*)(Wm + (size_t)(k0 + kb) * G4H + col0 + c4 * 4);
        }
        __syncthreads();

        #pragma unroll
        for (int k = 0; k < 16; ++k) {
            float a[8], b[8];
            #pragma unroll
            for (int i = 0; i < 8; ++i) a[i] = As[k][ty*8 + i];
            #pragma unroll
            for (int j = 0; j < 8; ++j) b[j] = Bs[k][tx*8 + j];
            #pragma unroll
            for (int i = 0; i < 8; ++i)
                #pragma unroll
                for (int j = 0; j < 8; ++j) acc[i][j] += a[i] * b[j];
        }
        __syncthreads();
    }

    #pragma unroll
    for (int i = 0; i < 8; ++i) {
        int grow = row0 + ty*8 + i;
        float* dst = xw + (size_t)grow * G4H + col0 + tx*8;
        #pragma unroll
        for (int j = 0; j < 8; j += 4) {
            float4 v;
            v.x = acc[i][j+0] + bias[col0 + tx*8 + j + 0];
            v.y = acc[i][j+1] + bias[col0 + tx*8 + j + 1];
            v.z = acc[i][j+2] + bias[col0 + tx*8 + j + 2];
            v.w = acc[i][j+3] + bias[col0 + tx*8 + j + 3];
            *(float4*)(dst + j) = v;
        }
    }
}

// ---------------------------------------------------------------------------
// Phase B: 8-wave persistent recurrent kernel, WAVE-AUTONOMOUS tagged
// dataflow — ZERO __syncthreads in the t-loop.
//
// Wave w = (batch b = w&3, unit-half g2 = w>>2): owns 32 output columns
// (4 gates x 8 units: cc = gi*16 + g2*8 + uu) with 2-way k-split across
// half-waves (lane<32: k in [0,256); lane>=32: k in [256,512)).
// Per step per wave: ingest full h[b] (8 tagged words/lane, interleaved),
// fire arrival on its wave-slot counter, stage to WAVE-PRIVATE hmy[w][512]
// (lgkmcnt(0)+sched_barrier only), 256-FMA dot, k-reduce via ONE
// shfl_down(32), per-lane activation, 4-shfl gate gather, WAR re-check,
// publish 8 tagged h words. No cross-wave LDS traffic, no barrier, no
// block-wide reduce.
// WAR: 8 counters/group (64B apart). Wave arrival = 1 relaxed system add
// after ingest verification (32 adds/line/step, fire-and-forget).
// Publisher of batch b checks reader slots {b, b+4} >= 32*gt (early-
// sampled after arrival, re-checked before publish). Chain is acyclic:
// publish(gt) <- {ingest(gt), arrivals(gt-1)} <- tags(gt-1) <- publish(gt-1).
// All cross-block traffic system-scope (L3) — the only verifiable scope
// on this platform (R13/R14 lesson).
// ---------------------------------------------------------------------------
__global__ __launch_bounds__(512, 1) void lstm_rec(
    const float* __restrict__ W,
    const float* __restrict__ h_init,
    const float* __restrict__ xw,
    float* __restrict__ out,
    float* __restrict__ c_ws,
    unsigned int* ctr,
    unsigned long long* hx,
    int t0, int nT)
{
    __shared__ float4 wlds[128][64];    // [k>>2][cc] = w[4k..4k+3][col(cc)]
    __shared__ float  hmy[8][512];      // wave-private h staging

    const int tid  = threadIdx.x;
    const int p    = blockIdx.x & 7;
    const int q    = blockIdx.x >> 3;
    const int w    = tid >> 6;
    const int lane = tid & 63;
    const int b    = w & 3;             // batch owner
    const int g2   = w >> 2;            // unit-half
    const int half = lane >> 5;         // k-half
    const int l5   = lane & 31;
    const int gi   = l5 >> 3;           // gate 0..3 (f,i,o,g)
    const int uu   = l5 & 7;            // unit within 8
    const int cc   = gi * 16 + g2 * 8 + uu;        // block-local col
    const int col  = gi * HH + q * 16 + g2 * 8 + uu; // global gate column

    // One-time: stage this block's recurrent W slice into LDS, k-packed.
    {
        const int c64 = tid & 63;
        const int kq = tid >> 6;
        const int cg = (c64 >> 4) * HH + q * 16 + (c64 & 15);  // global col of c64
        const float* Wr = W + (size_t)DD * G4H + cg;
        #pragma unroll 4
        for (int i = 0; i < 16; ++i) {
            const int k4 = i * 8 + kq;          // 0..127
            float4 v;
            v.x = Wr[(size_t)(4 * k4 + 0) * G4H];
            v.y = Wr[(size_t)(4 * k4 + 1) * G4H];
            v.z = Wr[(size_t)(4 * k4 + 2) * G4H];
            v.w = Wr[(size_t)(4 * k4 + 3) * G4H];
            wlds[k4][c64] = v;
        }
    }
    __syncthreads();   // only barrier: wlds visible to all waves

    // c state: lanes 0..7 hold c[batch 4p+b][unit q*16 + g2*8 + lane]
    float c = 0.f;
    if (t0 > 0 && lane < 8)
        c = c_ws[(size_t)(4 * p + b) * HH + q * 16 + g2 * 8 + lane];

    unsigned int* actr  = ctr + (p * 8 + w) * 16;        // my arrival counter
    unsigned int* rctr0 = ctr + (p * 8 + b) * 16;        // readers of batch b, g2=0
    unsigned int* rctr1 = ctr + (p * 8 + b + 4) * 16;    // readers of batch b, g2=1

    // Prologue: xw for step 0 (lanes 0..31 only — one col each).
    float xg = 0.f;
    if (l5 == lane)   // lane < 32
        xg = xw[((size_t)0 * BB + 4 * p + b) * G4H + col];

    for (int t = 0; t < nT; ++t) {
        const int gt = t0 + t;

        // Prefetch next step's x-part (independent; issues first).
        float xg_next = 0.f;
        if (lane < 32 && t + 1 < nT)
            xg_next = xw[((size_t)(t + 1) * BB + 4 * p + b) * G4H + col];

        // 1) Ingest full h[batch b]: 8 tagged words/lane, interleaved.
        float h0, h1, h2, h3, h4, h5, h6, h7;
        if (gt == 0) {
            h0 = h_init[lane +   0]; h1 = h_init[lane +  64];
            h2 = h_init[lane + 128]; h3 = h_init[lane + 192];
            h4 = h_init[lane + 256]; h5 = h_init[lane + 320];
            h6 = h_init[lane + 384]; h7 = h_init[lane + 448];
        } else {
            const unsigned int want = (unsigned int)gt;   // tag of h(gt-1)
            const unsigned long long* hs =
                hx + (size_t)((gt - 1) & 1) * (BB * HH) + (size_t)(4 * p + b) * HH;
            const unsigned long long* a0 = hs + lane;
            unsigned long long v0 = __hip_atomic_load(a0 +   0, __ATOMIC_RELAXED, __HIP_MEMORY_SCOPE_SYSTEM);
            unsigned long long v1 = __hip_atomic_load(a0 +  64, __ATOMIC_RELAXED, __HIP_MEMORY_SCOPE_SYSTEM);
            unsigned long long v2 = __hip_atomic_load(a0 + 128, __ATOMIC_RELAXED, __HIP_MEMORY_SCOPE_SYSTEM);
            unsigned long long v3 = __hip_atomic_load(a0 + 192, __ATOMIC_RELAXED, __HIP_MEMORY_SCOPE_SYSTEM);
            unsigned long long v4 = __hip_atomic_load(a0 + 256, __ATOMIC_RELAXED, __HIP_MEMORY_SCOPE_SYSTEM);
            unsigned long long v5 = __hip_atomic_load(a0 + 320, __ATOMIC_RELAXED, __HIP_MEMORY_SCOPE_SYSTEM);
            unsigned long long v6 = __hip_atomic_load(a0 + 384, __ATOMIC_RELAXED, __HIP_MEMORY_SCOPE_SYSTEM);
            unsigned long long v7 = __hip_atomic_load(a0 + 448, __ATOMIC_RELAXED, __HIP_MEMORY_SCOPE_SYSTEM);
            for (;;) {
                bool bad = false;
                if ((unsigned int)(v0 >> 32) != want) { bad = true; v0 = __hip_atomic_load(a0 +   0, __ATOMIC_RELAXED, __HIP_MEMORY_SCOPE_SYSTEM); }
                if ((unsigned int)(v1 >> 32) != want) { bad = true; v1 = __hip_atomic_load(a0 +  64, __ATOMIC_RELAXED, __HIP_MEMORY_SCOPE_SYSTEM); }
                if ((unsigned int)(v2 >> 32) != want) { bad = true; v2 = __hip_atomic_load(a0 + 128, __ATOMIC_RELAXED, __HIP_MEMORY_SCOPE_SYSTEM); }
                if ((unsigned int)(v3 >> 32) != want) { bad = true; v3 = __hip_atomic_load(a0 + 192, __ATOMIC_RELAXED, __HIP_MEMORY_SCOPE_SYSTEM); }
                if ((unsigned int)(v4 >> 32) != want) { bad = true; v4 = __hip_atomic_load(a0 + 256, __ATOMIC_RELAXED, __HIP_MEMORY_SCOPE_SYSTEM); }
                if ((unsigned int)(v5 >> 32) != want) { bad = true; v5 = __hip_atomic_load(a0 + 320, __ATOMIC_RELAXED, __HIP_MEMORY_SCOPE_SYSTEM); }
                if ((unsigned int)(v6 >> 32) != want) { bad = true; v6 = __hip_atomic_load(a0 + 384, __ATOMIC_RELAXED, __HIP_MEMORY_SCOPE_SYSTEM); }
                if ((unsigned int)(v7 >> 32) != want) { bad = true; v7 = __hip_atomic_load(a0 + 448, __ATOMIC_RELAXED, __HIP_MEMORY_SCOPE_SYSTEM); }
                if (!bad) break;
            }
            h0 = __uint_as_float((unsigned int)v0);
            h1 = __uint_as_float((unsigned int)v1);
            h2 = __uint_as_float((unsigned int)v2);
            h3 = __uint_as_float((unsigned int)v3);
            h4 = __uint_as_float((unsigned int)v4);
            h5 = __uint_as_float((unsigned int)v5);
            h6 = __uint_as_float((unsigned int)v6);
            h7 = __uint_as_float((unsigned int)v7);
        }

        // Arrival: this wave is done reading slot[(gt-1)&1]. Fire-and-forget.
        if (lane == 0)
            __hip_atomic_fetch_add(actr, 1u, __ATOMIC_RELAXED, __HIP_MEMORY_SCOPE_SYSTEM);

        // Early WAR sample (non-blocking; re-checked before publish).
        unsigned war0 = 0u, war1 = 0u;
        if (gt >= 2) {
            war0 = __hip_atomic_load(rctr0, __ATOMIC_RELAXED, __HIP_MEMORY_SCOPE_SYSTEM);
            war1 = __hip_atomic_load(rctr1, __ATOMIC_RELAXED, __HIP_MEMORY_SCOPE_SYSTEM);
        }

        // 2) Stage to wave-private LDS strip (no cross-wave dependency).
        hmy[w][lane +   0] = h0;  hmy[w][lane +  64] = h1;
        hmy[w][lane + 128] = h2;  hmy[w][lane + 192] = h3;
        hmy[w][lane + 256] = h4;  hmy[w][lane + 320] = h5;
        hmy[w][lane + 384] = h6;  hmy[w][lane + 448] = h7;
        asm volatile("s_waitcnt lgkmcnt(0)" ::: "memory");
        __builtin_amdgcn_sched_barrier(0);

        // 3) Half-k dot: 64 weight b128 + 64 uniform h b128, 256 FMA.
        float a0 = 0.f, a1 = 0.f, a2 = 0.f, a3 = 0.f;
        const int kbase = half * 64;
        #pragma unroll
        for (int j = 0; j < 16; ++j) {
            {
                const float4 wv = wlds[kbase + j][cc];
                const float4 hv = *(const float4*)&hmy[w][half * 256 + 4 * j];
                a0 += wv.x*hv.x; a0 += wv.y*hv.y; a0 += wv.z*hv.z; a0 += wv.w*hv.w;
            }
            {
                const float4 wv = wlds[kbase + 16 + j][cc];
                const float4 hv = *(const float4*)&hmy[w][half * 256 + 64 + 4 * j];
                a1 += wv.x*hv.x; a1 += wv.y*hv.y; a1 += wv.z*hv.z; a1 += wv.w*hv.w;
            }
            {
                const float4 wv = wlds[kbase + 32 + j][cc];
                const float4 hv = *(const float4*)&hmy[w][half * 256 + 128 + 4 * j];
                a2 += wv.x*hv.x; a2 += wv.y*hv.y; a2 += wv.z*hv.z; a2 += wv.w*hv.w;
            }
            {
                const float4 wv = wlds[kbase + 48 + j][cc];
                const float4 hv = *(const float4*)&hmy[w][half * 256 + 192 + 4 * j];
                a3 += wv.x*hv.x; a3 += wv.y*hv.y; a3 += wv.z*hv.z; a3 += wv.w*hv.w;
            }
        }
        float a = (a0 + a1) + (a2 + a3);

        // 4) k-reduce across half-waves: one shfl, no LDS, no barrier.
        a += __shfl_down(a, 32);

        // 5) Per-lane activation (lanes 0..31 meaningful), 4-shfl gather.
        const float g = a + xg;
        float act;
        if (gi == 3) act = 1.f - 2.f / (__expf(2.f * g) + 1.f);
        else         act = 1.f / (1.f + __expf(-g));

        const float fv = __shfl(act, uu);
        const float iv = __shfl(act, 8 + uu);
        const float ov = __shfl(act, 16 + uu);
        const float gv = __shfl(act, 24 + uu);

        // 6) WAR flow control: readers of slot[gt&1] (= h(gt-2)) are wave
        // slots {b, b+4} of all 32 blocks; need both counters >= 32*gt.
        if (gt >= 2) {
            const unsigned need = 32u * (unsigned)gt;
            while (war0 < need || war1 < need) {
                __builtin_amdgcn_s_sleep(1);
                war0 = __hip_atomic_load(rctr0, __ATOMIC_RELAXED, __HIP_MEMORY_SCOPE_SYSTEM);
                war1 = __hip_atomic_load(rctr1, __ATOMIC_RELAXED, __HIP_MEMORY_SCOPE_SYSTEM);
            }
        }
        asm volatile("" ::: "memory");

        // 7) Update + tagged publish (lanes 0..7: units g2*8 + lane).
        if (lane < 8) {
            c = fv * c + iv * gv;
            const float tc = 1.f - 2.f / (__expf(2.f * c) + 1.f);
            const float h = ov * tc;
            const unsigned long long pk =
                ((unsigned long long)(unsigned int)(gt + 1) << 32) |
                (unsigned long long)__float_as_uint(h);
            __hip_atomic_store(
                hx + (size_t)(gt & 1) * (BB * HH) + (size_t)(4 * p + b) * HH
                   + q * 16 + g2 * 8 + lane,
                pk, __ATOMIC_RELAXED, __HIP_MEMORY_SCOPE_SYSTEM);
            out[((size_t)(4 * p + b) * TT + gt) * HH + q * 16 + g2 * 8 + lane] = h;
        }

        xg = xg_next;
    }

    // Spill c state for the next chunk (kernel boundary = coherence).
    if (lane < 8)
        c_ws[(size_t)(4 * p + b) * HH + q * 16 + g2 * 8 + lane] = c;
}

// ---------------------------------------------------------------------------
extern "C" void kernel_launch(void* const* d_in, const int* in_sizes, int n_in,
                              void* d_out, int out_size, void* d_ws, size_t ws_size,
                              hipStream_t stream) {
    const float* x      = (const float*)d_in[0];
    // d_in[1] = input_paddings (unused)
    const float* W      = (const float*)d_in[2];
    const float* bias   = (const float*)d_in[3];
    const float* h_init = (const float*)d_in[4];
    float* out = (float*)d_out;

    // ws layout: xw | ctr (4 KB) | c_ws (64 KB) | hx (256 KB)
    static const int cand[] = {2048, 1024, 512, 256, 128, 64, 32, 16, 8, 4};
    const size_t extra = 4096 + 65536 + 262144;
    int CT = 4;
    for (int i = 0; i < 10; ++i) {
        if ((size_t)cand[i] * BB * G4H * 4 + extra <= ws_size) { CT = cand[i]; break; }
    }
    const size_t xw_bytes = (size_t)CT * BB * G4H * 4;
    float*              xw   = (float*)d_ws;
    unsigned int*       ctr  = (unsigned int*)((char*)d_ws + xw_bytes);
    float*              c_ws = (float*)((char*)d_ws + xw_bytes + 4096);
    unsigned long long* hx   = (unsigned long long*)((char*)d_ws + xw_bytes + 4096 + 65536);

    for (int t0 = 0; t0 < TT; t0 += CT) {
        dim3 g(G4H / 128, CT * BB / 128);
        gemm_xw<<<g, 256, 0, stream>>>(x, W, bias, xw, t0, ctr, hx);
        lstm_rec<<<256, 512, 0, stream>>>(W, h_init, xw, out, c_ws, ctr, hx, t0, CT);
    }
}

// Round 18
// 9570.612 us; speedup vs baseline: 4.0679x; 4.0679x over previous
//
#include <hip/hip_runtime.h>
#include <math.h>

// Problem constants (reference: B,T,D,H = 32,2048,512,512)
#define BB   32
#define TT   2048
#define DD   512
#define HH   512
#define G4H  2048   // 4*H

// ---------------------------------------------------------------------------
// Phase A: xw[t_local*32 + b][col] = sum_d X[b][t0+t][d] * W[d][col] + bias[col]
// fp32 tiled GEMM: 128x128 block tile, 16 K-step, 256 threads, 8x8 microtile.
// At t0==0 also zeroes the 8 group counters and the hx tag-exchange buffer.
// ---------------------------------------------------------------------------
__global__ __launch_bounds__(256, 2) void gemm_xw(
    const float* __restrict__ X, const float* __restrict__ Wm,
    const float* __restrict__ bias, float* __restrict__ xw,
    int t0, unsigned int* __restrict__ ctr, unsigned long long* __restrict__ hx)
{
    if (t0 == 0) {
        if (blockIdx.x == 0 && blockIdx.y == 0 && threadIdx.x < 8)
            ctr[threadIdx.x * 64] = 0u;
        if (blockIdx.x == 0) {
            const int n = 2 * BB * HH;               // 32768 u64 slots
            const int stride = gridDim.y * 256;
            for (int i = blockIdx.y * 256 + threadIdx.x; i < n; i += stride)
                hx[i] = 0ull;
        }
    }

    __shared__ float As[16][128];
    __shared__ float Bs[16][128];

    const int tid  = threadIdx.x;
    const int row0 = blockIdx.y * 128;   // rows: (t_local, b) t-major
    const int col0 = blockIdx.x * 128;
    const int tx = tid & 15;
    const int ty = tid >> 4;

    float acc[8][8];
    #pragma unroll
    for (int i = 0; i < 8; ++i)
        #pragma unroll
        for (int j = 0; j < 8; ++j) acc[i][j] = 0.f;

    for (int k0 = 0; k0 < DD; k0 += 16) {
        #pragma unroll
        for (int i = 0; i < 2; ++i) {
            int qa = tid + i * 256;          // 0..511 quads
            int r  = qa >> 2, kq = qa & 3;
            int grow = row0 + r;
            int b = grow & 31, tl = grow >> 5;
            const float4 a = *(const float4*)(X + ((size_t)b * TT + t0 + tl) * DD + k0 + kq * 4);
            As[kq*4+0][r] = a.x; As[kq*4+1][r] = a.y;
            As[kq*4+2][r] = a.z; As[kq*4+3][r] = a.w;

            int qb = tid + i * 256;
            int kb = qb >> 5, c4 = qb & 31;
            *(float4*)&Bs[kb][c4*4] =
                *(const float4*)(Wm + (size_t)(k0 + kb) * G4H + col0 + c4 * 4);
        }
        __syncthreads();

        #pragma unroll
        for (int k = 0; k < 16; ++k) {
            float a[8], b[8];
            #pragma unroll
            for (int i = 0; i < 8; ++i) a[i] = As[k][ty*8 + i];
            #pragma unroll
            for (int j = 0; j < 8; ++j) b[j] = Bs[k][tx*8 + j];
            #pragma unroll
            for (int i = 0; i < 8; ++i)
                #pragma unroll
                for (int j = 0; j < 8; ++j) acc[i][j] += a[i] * b[j];
        }
        __syncthreads();
    }

    #pragma unroll
    for (int i = 0; i < 8; ++i) {
        int grow = row0 + ty*8 + i;
        float* dst = xw + (size_t)grow * G4H + col0 + tx*8;
        #pragma unroll
        for (int j = 0; j < 8; j += 4) {
            float4 v;
            v.x = acc[i][j+0] + bias[col0 + tx*8 + j + 0];
            v.y = acc[i][j+1] + bias[col0 + tx*8 + j + 1];
            v.z = acc[i][j+2] + bias[col0 + tx*8 + j + 2];
            v.w = acc[i][j+3] + bias[col0 + tx*8 + j + 3];
            *(float4*)(dst + j) = v;
        }
    }
}

// ---------------------------------------------------------------------------
// Phase B: 8-wave (512-thread) persistent recurrent kernel, tagged-dataflow
// h exchange — the R16 kernel (known good, 3.85 us/step) with ONE change:
// the tag-poll retry loop is restructured from conditional per-word reloads
// (divergent branch around each load -> up to 4 serialized ~600cy L3 RTTs
// per iteration) to STRAIGHT-LINE PARALLEL reloads: every iteration issues
// all 4 loads back-to-back (concurrently in flight), then one combined
// check. Re-reading an already-good word is harmless (producer writes each
// slot once per step; tag match pins the value). Protocol unchanged.
// ALL cross-block traffic is system-scope (L3 point) — the only scope with
// verifiable progress on this platform (XCD/sc0 experiment closed, R13/R14;
// wave-autonomous restructure closed, R17: 8-way wlds bank conflicts).
// ---------------------------------------------------------------------------
__global__ __launch_bounds__(512, 1) void lstm_rec(
    const float* __restrict__ W,
    const float* __restrict__ h_init,
    const float* __restrict__ xw,
    float* __restrict__ out,
    float* __restrict__ c_ws,
    unsigned int* ctr,
    unsigned long long* hx,
    int t0, int nT)
{
    __shared__ float4 wlds[128][64];    // [k>>2][col_local] = w[4k..4k+3][col]
    __shared__ float4 hb4[512];         // [k] = {h_b0,h_b1,h_b2,h_b3}; [w*64..] wave-local
    __shared__ float  red[2][8][4][64]; // [parity][kslice-wave][batch][lane]

    const int tid  = threadIdx.x;
    const int p    = blockIdx.x & 7;
    const int q    = blockIdx.x >> 3;
    const int w    = tid >> 6;          // wave id = K-slice; w<4 also = batch owner
    const int lane = tid & 63;
    const int gi   = lane >> 4;
    const int u    = lane & 15;
    const int col  = gi * HH + q * 16 + u;   // this lane's global gate column

    // One-time: stage this block's recurrent W slice into LDS, k-packed.
    {
        const int cc = tid & 63;
        const int kq = tid >> 6;
        const int cg = (cc >> 4) * HH + q * 16 + (cc & 15);  // global col of cc
        const float* Wr = W + (size_t)DD * G4H + cg;
        #pragma unroll 4
        for (int i = 0; i < 16; ++i) {
            const int k4 = i * 8 + kq;          // 0..127
            float4 v;
            v.x = Wr[(size_t)(4 * k4 + 0) * G4H];
            v.y = Wr[(size_t)(4 * k4 + 1) * G4H];
            v.z = Wr[(size_t)(4 * k4 + 2) * G4H];
            v.w = Wr[(size_t)(4 * k4 + 3) * G4H];
            wlds[k4][cc] = v;
        }
    }
    __syncthreads();

    // c state: lanes 0..15 of waves 0-3 hold c[batch 4p+w][unit q*16+lane]
    float c = 0.f;
    if (t0 > 0 && w < 4 && lane < 16)
        c = c_ws[(size_t)(4 * p + w) * HH + q * 16 + lane];

    unsigned int* myctr = ctr + p * 64;
    const int hoff = w * 64 + lane;       // this lane's h element (k-slice)

    // Prologue: load xw for step 0 (batch-owner waves only).
    float xg = 0.f;
    if (w < 4)
        xg = xw[((size_t)0 * BB + 4 * p + w) * G4H + col];

    for (int t = 0; t < nT; ++t) {
        const int gt = t0 + t;

        // Prefetch next step's x-part (independent; issues first).
        float xg_next = 0.f;
        if (w < 4 && t + 1 < nT)
            xg_next = xw[((size_t)(t + 1) * BB + 4 * p + w) * G4H + col];

        // 1) h ingest via tagged dataflow: 4 words/lane (one per batch).
        //    PARALLEL-reload poll: all 4 loads issued back-to-back each
        //    iteration, one combined check -> ~1 L3 RTT per iteration.
        float h0v, h1v, h2v, h3v;
        if (gt == 0) {
            const float hv = h_init[hoff];
            h0v = hv; h1v = hv; h2v = hv; h3v = hv;
        } else {
            const unsigned int want = (unsigned int)gt;   // tag of h(gt-1)
            const unsigned long long* hs = hx + (size_t)((gt - 1) & 1) * (BB * HH);
            const unsigned long long* a0 = hs + (size_t)(4 * p + 0) * HH + hoff;
            const unsigned long long* a1 = hs + (size_t)(4 * p + 1) * HH + hoff;
            const unsigned long long* a2 = hs + (size_t)(4 * p + 2) * HH + hoff;
            const unsigned long long* a3 = hs + (size_t)(4 * p + 3) * HH + hoff;
            unsigned long long v0, v1, v2, v3;
            bool need = true;
            do {
                v0 = __hip_atomic_load(a0, __ATOMIC_RELAXED, __HIP_MEMORY_SCOPE_SYSTEM);
                v1 = __hip_atomic_load(a1, __ATOMIC_RELAXED, __HIP_MEMORY_SCOPE_SYSTEM);
                v2 = __hip_atomic_load(a2, __ATOMIC_RELAXED, __HIP_MEMORY_SCOPE_SYSTEM);
                v3 = __hip_atomic_load(a3, __ATOMIC_RELAXED, __HIP_MEMORY_SCOPE_SYSTEM);
                need = ((unsigned int)(v0 >> 32) != want) |
                       ((unsigned int)(v1 >> 32) != want) |
                       ((unsigned int)(v2 >> 32) != want) |
                       ((unsigned int)(v3 >> 32) != want);
            } while (need);
            h0v = __uint_as_float((unsigned int)v0);
            h1v = __uint_as_float((unsigned int)v1);
            h2v = __uint_as_float((unsigned int)v2);
            h3v = __uint_as_float((unsigned int)v3);
        }

        // WAR counter: non-blocking early sample (re-checked after reduce).
        unsigned warv = 0;
        if (w < 4 && gt >= 2)
            warv = __hip_atomic_load(myctr, __ATOMIC_RELAXED, __HIP_MEMORY_SCOPE_SYSTEM);

        // 2) Wave-local stage: ONE ds_write_b128 (unit-major, 4 batches).
        float4 hv4; hv4.x = h0v; hv4.y = h1v; hv4.z = h2v; hv4.w = h3v;
        hb4[hoff] = hv4;
        asm volatile("s_waitcnt lgkmcnt(0)" ::: "memory");
        __builtin_amdgcn_sched_barrier(0);

        // 3) K-slice dot: 16 per-lane wlds b128 + 4 broadcast b128 per j,
        //    256 FMA per lane. hb4 row r = {h_b0..h_b3} at k=r.
        const int base = w * 16;
        float a0 = 0.f, a1 = 0.f, a2 = 0.f, a3 = 0.f;
        #pragma unroll
        for (int j = 0; j < 16; ++j) {
            const float4 wv = wlds[base + j][lane];
            const float4 r0 = hb4[w * 64 + 4 * j + 0];
            const float4 r1 = hb4[w * 64 + 4 * j + 1];
            const float4 r2 = hb4[w * 64 + 4 * j + 2];
            const float4 r3 = hb4[w * 64 + 4 * j + 3];
            a0 += wv.x*r0.x; a1 += wv.x*r0.y; a2 += wv.x*r0.z; a3 += wv.x*r0.w;
            a0 += wv.y*r1.x; a1 += wv.y*r1.y; a2 += wv.y*r1.z; a3 += wv.y*r1.w;
            a0 += wv.z*r2.x; a1 += wv.z*r2.y; a2 += wv.z*r2.z; a3 += wv.z*r2.w;
            a0 += wv.w*r3.x; a1 += wv.w*r3.y; a2 += wv.w*r3.z; a3 += wv.w*r3.w;
        }

        // 4) Cross-wave reduce through parity-double-buffered red[].
        const int par = gt & 1;
        red[par][w][0][lane] = a0; red[par][w][1][lane] = a1;
        red[par][w][2][lane] = a2; red[par][w][3][lane] = a3;
        __syncthreads();                         // the ONE block barrier/step

        // Arrival: this block has consumed h(gt-1). 1 add/block/step.
        if (tid == 0)
            __hip_atomic_fetch_add(myctr, 1u, __ATOMIC_RELAXED, __HIP_MEMORY_SCOPE_SYSTEM);

        if (w < 4) {
            float g = xg;
            #pragma unroll
            for (int s = 0; s < 8; ++s) g += red[par][s][w][lane];

            // Per-lane activation BEFORE gather: lane's own gate type only.
            float act;
            if (gi == 3) act = 1.f - 2.f / (__expf(2.f * g) + 1.f);
            else         act = 1.f / (1.f + __expf(-g));

            const int ul = lane & 15;
            const float fv = __shfl(act, ul);
            const float iv = __shfl(act, ul + 16);
            const float ov = __shfl(act, ul + 32);
            const float gv = __shfl(act, ul + 48);

            // WAR flow control (slot gt&1 holds h(gt-2)): early sample
            // normally satisfies it; retry with s_sleep (rare path).
            if (gt >= 2) {
                const unsigned need = 32u * (unsigned)gt;
                while (warv < need) {
                    __builtin_amdgcn_s_sleep(1);
                    warv = __hip_atomic_load(myctr, __ATOMIC_RELAXED, __HIP_MEMORY_SCOPE_SYSTEM);
                }
            }
            asm volatile("" ::: "memory");

            if (lane < 16) {
                c = fv * c + iv * gv;
                const float tc = 1.f - 2.f / (__expf(2.f * c) + 1.f);
                const float h = ov * tc;
                // Tagged publish: value+tag in one 8B relaxed system store.
                const unsigned long long pk =
                    ((unsigned long long)(unsigned int)(gt + 1) << 32) |
                    (unsigned long long)__float_as_uint(h);
                __hip_atomic_store(
                    hx + (size_t)(gt & 1) * (BB * HH) + (size_t)(4 * p + w) * HH + q * 16 + lane,
                    pk, __ATOMIC_RELAXED, __HIP_MEMORY_SCOPE_SYSTEM);
                // Output store: not read in-kernel, off the sync path.
                out[((size_t)(4 * p + w) * TT + gt) * HH + q * 16 + lane] = h;
            }
        }

        xg = xg_next;
    }

    // Spill c state for the next chunk (kernel boundary = coherence).
    if (w < 4 && lane < 16)
        c_ws[(size_t)(4 * p + w) * HH + q * 16 + lane] = c;
}

// ---------------------------------------------------------------------------
extern "C" void kernel_launch(void* const* d_in, const int* in_sizes, int n_in,
                              void* d_out, int out_size, void* d_ws, size_t ws_size,
                              hipStream_t stream) {
    const float* x      = (const float*)d_in[0];
    // d_in[1] = input_paddings (unused)
    const float* W      = (const float*)d_in[2];
    const float* bias   = (const float*)d_in[3];
    const float* h_init = (const float*)d_in[4];
    float* out = (float*)d_out;

    // ws layout: xw (CT*32*2048*4 B) | ctr (2 KB) | c_ws (64 KB) | hx (256 KB)
    static const int cand[] = {2048, 1024, 512, 256, 128, 64, 32, 16, 8, 4};
    const size_t extra = 2048 + 65536 + 262144;
    int CT = 4;
    for (int i = 0; i < 10; ++i) {
        if ((size_t)cand[i] * BB * G4H * 4 + extra <= ws_size) { CT = cand[i]; break; }
    }
    const size_t xw_bytes = (size_t)CT * BB * G4H * 4;
    float*              xw   = (float*)d_ws;
    unsigned int*       ctr  = (unsigned int*)((char*)d_ws + xw_bytes);
    float*              c_ws = (float*)((char*)d_ws + xw_bytes + 2048);
    unsigned long long* hx   = (unsigned long long*)((char*)d_ws + xw_bytes + 2048 + 65536);

    for (int t0 = 0; t0 < TT; t0 += CT) {
        dim3 g(G4H / 128, CT * BB / 128);
        gemm_xw<<<g, 256, 0, stream>>>(x, W, bias, xw, t0, ctr, hx);
        lstm_rec<<<256, 512, 0, stream>>>(W, h_init, xw, out, c_ws, ctr, hx, t0, CT);
    }
}

// Round 19
// 8729.926 us; speedup vs baseline: 4.4596x; 1.0963x over previous
//
#include <hip/hip_runtime.h>
#include <math.h>

// Problem constants (reference: B,T,D,H = 32,2048,512,512)
#define BB   32
#define TT   2048
#define DD   512
#define HH   512
#define G4H  2048   // 4*H

// ---------------------------------------------------------------------------
// Phase A: xw[t_local*32 + b][col] = sum_d X[b][t0+t][d] * W[d][col] + bias[col]
// fp32 tiled GEMM: 128x128 block tile, 16 K-step, 256 threads, 8x8 microtile.
// At t0==0 also zeroes the hx tag-exchange buffer (tags stored are >=1, so
// zeroed/poisoned/leftover words can never be accepted before the real
// producer writes them).
// ---------------------------------------------------------------------------
__global__ __launch_bounds__(256, 2) void gemm_xw(
    const float* __restrict__ X, const float* __restrict__ Wm,
    const float* __restrict__ bias, float* __restrict__ xw,
    int t0, unsigned long long* __restrict__ hx)
{
    if (t0 == 0 && blockIdx.x == 0) {
        const int n = 2 * BB * HH;               // 32768 u64 slots
        const int stride = gridDim.y * 256;
        for (int i = blockIdx.y * 256 + threadIdx.x; i < n; i += stride)
            hx[i] = 0ull;
    }

    __shared__ float As[16][128];
    __shared__ float Bs[16][128];

    const int tid  = threadIdx.x;
    const int row0 = blockIdx.y * 128;   // rows: (t_local, b) t-major
    const int col0 = blockIdx.x * 128;
    const int tx = tid & 15;
    const int ty = tid >> 4;

    float acc[8][8];
    #pragma unroll
    for (int i = 0; i < 8; ++i)
        #pragma unroll
        for (int j = 0; j < 8; ++j) acc[i][j] = 0.f;

    for (int k0 = 0; k0 < DD; k0 += 16) {
        #pragma unroll
        for (int i = 0; i < 2; ++i) {
            int qa = tid + i * 256;          // 0..511 quads
            int r  = qa >> 2, kq = qa & 3;
            int grow = row0 + r;
            int b = grow & 31, tl = grow >> 5;
            const float4 a = *(const float4*)(X + ((size_t)b * TT + t0 + tl) * DD + k0 + kq * 4);
            As[kq*4+0][r] = a.x; As[kq*4+1][r] = a.y;
            As[kq*4+2][r] = a.z; As[kq*4+3][r] = a.w;

            int qb = tid + i * 256;
            int kb = qb >> 5, c4 = qb & 31;
            *(float4*)&Bs[kb][c4*4] =
                *(const float4*)(Wm + (size_t)(k0 + kb) * G4H + col0 + c4 * 4);
        }
        __syncthreads();

        #pragma unroll
        for (int k = 0; k < 16; ++k) {
            float a[8], b[8];
            #pragma unroll
            for (int i = 0; i < 8; ++i) a[i] = As[k][ty*8 + i];
            #pragma unroll
            for (int j = 0; j < 8; ++j) b[j] = Bs[k][tx*8 + j];
            #pragma unroll
            for (int i = 0; i < 8; ++i)
                #pragma unroll
                for (int j = 0; j < 8; ++j) acc[i][j] += a[i] * b[j];
        }
        __syncthreads();
    }

    #pragma unroll
    for (int i = 0; i < 8; ++i) {
        int grow = row0 + ty*8 + i;
        float* dst = xw + (size_t)grow * G4H + col0 + tx*8;
        #pragma unroll
        for (int j = 0; j < 8; j += 4) {
            float4 v;
            v.x = acc[i][j+0] + bias[col0 + tx*8 + j + 0];
            v.y = acc[i][j+1] + bias[col0 + tx*8 + j + 1];
            v.z = acc[i][j+2] + bias[col0 + tx*8 + j + 2];
            v.w = acc[i][j+3] + bias[col0 + tx*8 + j + 3];
            *(float4*)(dst + j) = v;
        }
    }
}

// ---------------------------------------------------------------------------
// Phase B: 8-wave (512-thread) persistent recurrent kernel, tagged-dataflow
// h exchange — R16 kernel (known good, 3.85 us/step) with the WAR/arrival
// counter machinery DELETED (and R18's poll change reverted).
//
// Why the counters are redundant (WAR safety carried by the tags):
// publisher X at step gt overwrites slot[gt&1] = h(gt-2). Before publishing,
// X's 8 waves have tag-verified h(gt-1) from ALL 32 blocks (4 producers per
// wave, union = 32; the reduce barrier joins the waves). Block Y's publish
// of h(gt-1) is DATA-DEPENDENT on Y's complete register-verified reads of
// h(gt-2) (published value <- gates <- red <- dot <- staged h). Hence
// "X observed all h(gt-1) tags" => "every block finished reading h(gt-2)".
// No counter needed; strictly fewer wait conditions than R16 (no new
// deadlock risk — tag-poll exit conditions unchanged).
//
// ALL cross-block traffic is system-scope (L3 point) — the only scope with
// verifiable progress on this platform (XCD/sc0 closed R13/R14; wave-
// autonomous restructure closed R17: 8-way wlds bank conflicts; parallel-
// reload poll closed R18: regression).
// ---------------------------------------------------------------------------
__global__ __launch_bounds__(512, 1) void lstm_rec(
    const float* __restrict__ W,
    const float* __restrict__ h_init,
    const float* __restrict__ xw,
    float* __restrict__ out,
    float* __restrict__ c_ws,
    unsigned long long* hx,
    int t0, int nT)
{
    __shared__ float4 wlds[128][64];    // [k>>2][col_local] = w[4k..4k+3][col]
    __shared__ float4 hb4[512];         // [k] = {h_b0,h_b1,h_b2,h_b3}; [w*64..] wave-local
    __shared__ float  red[2][8][4][64]; // [parity][kslice-wave][batch][lane]

    const int tid  = threadIdx.x;
    const int p    = blockIdx.x & 7;
    const int q    = blockIdx.x >> 3;
    const int w    = tid >> 6;          // wave id = K-slice; w<4 also = batch owner
    const int lane = tid & 63;
    const int gi   = lane >> 4;
    const int u    = lane & 15;
    const int col  = gi * HH + q * 16 + u;   // this lane's global gate column

    // One-time: stage this block's recurrent W slice into LDS, k-packed.
    {
        const int cc = tid & 63;
        const int kq = tid >> 6;
        const int cg = (cc >> 4) * HH + q * 16 + (cc & 15);  // global col of cc
        const float* Wr = W + (size_t)DD * G4H + cg;
        #pragma unroll 4
        for (int i = 0; i < 16; ++i) {
            const int k4 = i * 8 + kq;          // 0..127
            float4 v;
            v.x = Wr[(size_t)(4 * k4 + 0) * G4H];
            v.y = Wr[(size_t)(4 * k4 + 1) * G4H];
            v.z = Wr[(size_t)(4 * k4 + 2) * G4H];
            v.w = Wr[(size_t)(4 * k4 + 3) * G4H];
            wlds[k4][cc] = v;
        }
    }
    __syncthreads();

    // c state: lanes 0..15 of waves 0-3 hold c[batch 4p+w][unit q*16+lane]
    float c = 0.f;
    if (t0 > 0 && w < 4 && lane < 16)
        c = c_ws[(size_t)(4 * p + w) * HH + q * 16 + lane];

    const int hoff = w * 64 + lane;       // this lane's h element (k-slice)

    // Prologue: load xw for step 0 (batch-owner waves only).
    float xg = 0.f;
    if (w < 4)
        xg = xw[((size_t)0 * BB + 4 * p + w) * G4H + col];

    for (int t = 0; t < nT; ++t) {
        const int gt = t0 + t;

        // Prefetch next step's x-part (independent; issues first).
        float xg_next = 0.f;
        if (w < 4 && t + 1 < nT)
            xg_next = xw[((size_t)(t + 1) * BB + 4 * p + w) * G4H + col];

        // 1) h ingest via tagged dataflow: 4 words/lane (one per batch).
        //    Conditional per-word reload (R16 form — only stragglers refetch).
        float h0v, h1v, h2v, h3v;
        if (gt == 0) {
            const float hv = h_init[hoff];
            h0v = hv; h1v = hv; h2v = hv; h3v = hv;
        } else {
            const unsigned int want = (unsigned int)gt;   // tag of h(gt-1)
            const unsigned long long* hs = hx + (size_t)((gt - 1) & 1) * (BB * HH);
            const unsigned long long* a0 = hs + (size_t)(4 * p + 0) * HH + hoff;
            const unsigned long long* a1 = hs + (size_t)(4 * p + 1) * HH + hoff;
            const unsigned long long* a2 = hs + (size_t)(4 * p + 2) * HH + hoff;
            const unsigned long long* a3 = hs + (size_t)(4 * p + 3) * HH + hoff;
            unsigned long long v0 = __hip_atomic_load(a0, __ATOMIC_RELAXED, __HIP_MEMORY_SCOPE_SYSTEM);
            unsigned long long v1 = __hip_atomic_load(a1, __ATOMIC_RELAXED, __HIP_MEMORY_SCOPE_SYSTEM);
            unsigned long long v2 = __hip_atomic_load(a2, __ATOMIC_RELAXED, __HIP_MEMORY_SCOPE_SYSTEM);
            unsigned long long v3 = __hip_atomic_load(a3, __ATOMIC_RELAXED, __HIP_MEMORY_SCOPE_SYSTEM);
            for (;;) {
                bool bad = false;
                if ((unsigned int)(v0 >> 32) != want) { bad = true; v0 = __hip_atomic_load(a0, __ATOMIC_RELAXED, __HIP_MEMORY_SCOPE_SYSTEM); }
                if ((unsigned int)(v1 >> 32) != want) { bad = true; v1 = __hip_atomic_load(a1, __ATOMIC_RELAXED, __HIP_MEMORY_SCOPE_SYSTEM); }
                if ((unsigned int)(v2 >> 32) != want) { bad = true; v2 = __hip_atomic_load(a2, __ATOMIC_RELAXED, __HIP_MEMORY_SCOPE_SYSTEM); }
                if ((unsigned int)(v3 >> 32) != want) { bad = true; v3 = __hip_atomic_load(a3, __ATOMIC_RELAXED, __HIP_MEMORY_SCOPE_SYSTEM); }
                if (!bad) break;
            }
            h0v = __uint_as_float((unsigned int)v0);
            h1v = __uint_as_float((unsigned int)v1);
            h2v = __uint_as_float((unsigned int)v2);
            h3v = __uint_as_float((unsigned int)v3);
        }

        // 2) Wave-local stage: ONE ds_write_b128 (unit-major, 4 batches).
        float4 hv4; hv4.x = h0v; hv4.y = h1v; hv4.z = h2v; hv4.w = h3v;
        hb4[hoff] = hv4;
        asm volatile("s_waitcnt lgkmcnt(0)" ::: "memory");
        __builtin_amdgcn_sched_barrier(0);

        // 3) K-slice dot: 16 per-lane wlds b128 + 4 broadcast b128 per j,
        //    256 FMA per lane. hb4 row r = {h_b0..h_b3} at k=r.
        const int base = w * 16;
        float a0 = 0.f, a1 = 0.f, a2 = 0.f, a3 = 0.f;
        #pragma unroll
        for (int j = 0; j < 16; ++j) {
            const float4 wv = wlds[base + j][lane];
            const float4 r0 = hb4[w * 64 + 4 * j + 0];
            const float4 r1 = hb4[w * 64 + 4 * j + 1];
            const float4 r2 = hb4[w * 64 + 4 * j + 2];
            const float4 r3 = hb4[w * 64 + 4 * j + 3];
            a0 += wv.x*r0.x; a1 += wv.x*r0.y; a2 += wv.x*r0.z; a3 += wv.x*r0.w;
            a0 += wv.y*r1.x; a1 += wv.y*r1.y; a2 += wv.y*r1.z; a3 += wv.y*r1.w;
            a0 += wv.z*r2.x; a1 += wv.z*r2.y; a2 += wv.z*r2.z; a3 += wv.z*r2.w;
            a0 += wv.w*r3.x; a1 += wv.w*r3.y; a2 += wv.w*r3.z; a3 += wv.w*r3.w;
        }

        // 4) Cross-wave reduce through parity-double-buffered red[].
        const int par = gt & 1;
        red[par][w][0][lane] = a0; red[par][w][1][lane] = a1;
        red[par][w][2][lane] = a2; red[par][w][3][lane] = a3;
        __syncthreads();                         // the ONE block barrier/step

        if (w < 4) {
            float g = xg;
            #pragma unroll
            for (int s = 0; s < 8; ++s) g += red[par][s][w][lane];

            // Per-lane activation BEFORE gather: lane's own gate type only.
            float act;
            if (gi == 3) act = 1.f - 2.f / (__expf(2.f * g) + 1.f);
            else         act = 1.f / (1.f + __expf(-g));

            const int ul = lane & 15;
            const float fv = __shfl(act, ul);
            const float iv = __shfl(act, ul + 16);
            const float ov = __shfl(act, ul + 32);
            const float gv = __shfl(act, ul + 48);

            if (lane < 16) {
                c = fv * c + iv * gv;
                const float tc = 1.f - 2.f / (__expf(2.f * c) + 1.f);
                const float h = ov * tc;
                // Tagged publish: value+tag in one 8B relaxed system store.
                // WAR safety is carried by the tags (see header comment).
                const unsigned long long pk =
                    ((unsigned long long)(unsigned int)(gt + 1) << 32) |
                    (unsigned long long)__float_as_uint(h);
                __hip_atomic_store(
                    hx + (size_t)(gt & 1) * (BB * HH) + (size_t)(4 * p + w) * HH + q * 16 + lane,
                    pk, __ATOMIC_RELAXED, __HIP_MEMORY_SCOPE_SYSTEM);
                // Output store: not read in-kernel, off the sync path.
                out[((size_t)(4 * p + w) * TT + gt) * HH + q * 16 + lane] = h;
            }
        }

        xg = xg_next;
    }

    // Spill c state for the next chunk (kernel boundary = coherence).
    if (w < 4 && lane < 16)
        c_ws[(size_t)(4 * p + w) * HH + q * 16 + lane] = c;
}

// ---------------------------------------------------------------------------
extern "C" void kernel_launch(void* const* d_in, const int* in_sizes, int n_in,
                              void* d_out, int out_size, void* d_ws, size_t ws_size,
                              hipStream_t stream) {
    const float* x      = (const float*)d_in[0];
    // d_in[1] = input_paddings (unused)
    const float* W      = (const float*)d_in[2];
    const float* bias   = (const float*)d_in[3];
    const float* h_init = (const float*)d_in[4];
    float* out = (float*)d_out;

    // ws layout: xw (CT*32*2048*4 B) | c_ws (64 KB) | hx (256 KB)
    static const int cand[] = {2048, 1024, 512, 256, 128, 64, 32, 16, 8, 4};
    const size_t extra = 65536 + 262144;
    int CT = 4;
    for (int i = 0; i < 10; ++i) {
        if ((size_t)cand[i] * BB * G4H * 4 + extra <= ws_size) { CT = cand[i]; break; }
    }
    const size_t xw_bytes = (size_t)CT * BB * G4H * 4;
    float*              xw   = (float*)d_ws;
    float*              c_ws = (float*)((char*)d_ws + xw_bytes);
    unsigned long long* hx   = (unsigned long long*)((char*)d_ws + xw_bytes + 65536);

    for (int t0 = 0; t0 < TT; t0 += CT) {
        dim3 g(G4H / 128, CT * BB / 128);
        gemm_xw<<<g, 256, 0, stream>>>(x, W, bias, xw, t0, hx);
        lstm_rec<<<256, 512, 0, stream>>>(W, h_init, xw, out, c_ws, hx, t0, CT);
    }
}

// Round 20
// 8622.869 us; speedup vs baseline: 4.5150x; 1.0124x over previous
//
#include <hip/hip_runtime.h>
#include <math.h>

// Problem constants (reference: B,T,D,H = 32,2048,512,512)
#define BB   32
#define TT   2048
#define DD   512
#define HH   512
#define G4H  2048   // 4*H

// ---------------------------------------------------------------------------
// Phase A: xw[t_local*32 + b][col] = sum_d X[b][t0+t][d] * W[d][col] + bias[col]
// fp32 tiled GEMM: 128x128 block tile, 16 K-step, 256 threads, 8x8 microtile.
// At t0==0 also zeroes the hx tag-exchange buffer (tags stored are >=1, so
// zeroed/poisoned/leftover words can never be accepted before the real
// producer writes them).
// ---------------------------------------------------------------------------
__global__ __launch_bounds__(256, 2) void gemm_xw(
    const float* __restrict__ X, const float* __restrict__ Wm,
    const float* __restrict__ bias, float* __restrict__ xw,
    int t0, unsigned long long* __restrict__ hx)
{
    if (t0 == 0 && blockIdx.x == 0) {
        const int n = 2 * BB * HH;               // 32768 u64 slots
        const int stride = gridDim.y * 256;
        for (int i = blockIdx.y * 256 + threadIdx.x; i < n; i += stride)
            hx[i] = 0ull;
    }

    __shared__ float As[16][128];
    __shared__ float Bs[16][128];

    const int tid  = threadIdx.x;
    const int row0 = blockIdx.y * 128;   // rows: (t_local, b) t-major
    const int col0 = blockIdx.x * 128;
    const int tx = tid & 15;
    const int ty = tid >> 4;

    float acc[8][8];
    #pragma unroll
    for (int i = 0; i < 8; ++i)
        #pragma unroll
        for (int j = 0; j < 8; ++j) acc[i][j] = 0.f;

    for (int k0 = 0; k0 < DD; k0 += 16) {
        #pragma unroll
        for (int i = 0; i < 2; ++i) {
            int qa = tid + i * 256;          // 0..511 quads
            int r  = qa >> 2, kq = qa & 3;
            int grow = row0 + r;
            int b = grow & 31, tl = grow >> 5;
            const float4 a = *(const float4*)(X + ((size_t)b * TT + t0 + tl) * DD + k0 + kq * 4);
            As[kq*4+0][r] = a.x; As[kq*4+1][r] = a.y;
            As[kq*4+2][r] = a.z; As[kq*4+3][r] = a.w;

            int qb = tid + i * 256;
            int kb = qb >> 5, c4 = qb & 31;
            *(float4*)&Bs[kb][c4*4] =
                *(const float4*)(Wm + (size_t)(k0 + kb) * G4H + col0 + c4 * 4);
        }
        __syncthreads();

        #pragma unroll
        for (int k = 0; k < 16; ++k) {
            float a[8], b[8];
            #pragma unroll
            for (int i = 0; i < 8; ++i) a[i] = As[k][ty*8 + i];
            #pragma unroll
            for (int j = 0; j < 8; ++j) b[j] = Bs[k][tx*8 + j];
            #pragma unroll
            for (int i = 0; i < 8; ++i)
                #pragma unroll
                for (int j = 0; j < 8; ++j) acc[i][j] += a[i] * b[j];
        }
        __syncthreads();
    }

    #pragma unroll
    for (int i = 0; i < 8; ++i) {
        int grow = row0 + ty*8 + i;
        float* dst = xw + (size_t)grow * G4H + col0 + tx*8;
        #pragma unroll
        for (int j = 0; j < 8; j += 4) {
            float4 v;
            v.x = acc[i][j+0] + bias[col0 + tx*8 + j + 0];
            v.y = acc[i][j+1] + bias[col0 + tx*8 + j + 1];
            v.z = acc[i][j+2] + bias[col0 + tx*8 + j + 2];
            v.w = acc[i][j+3] + bias[col0 + tx*8 + j + 3];
            *(float4*)(dst + j) = v;
        }
    }
}

// ---------------------------------------------------------------------------
// Phase B: 8-wave (512-thread) persistent recurrent kernel, tagged-dataflow
// h exchange — R19 kernel (known good) with ONE change: the per-step
// __syncthreads (which emits s_waitcnt vmcnt(0) lgkmcnt(0) before s_barrier,
// force-draining in-flight GLOBAL ops: xg prefetch, out/hx stores) is
// replaced by the targeted join:
//     s_waitcnt lgkmcnt(0)  (own red[] LDS writes)
//   + raw s_barrier          (execution join; LDS is physically shared)
//   + sched_barrier(0)       (rule #18: no compiler motion across)
// Global ops stay in flight across the barrier. Audit: the only cross-wave
// dependency at the join is red[] (LDS, covered); publish/out stores and
// the xg prefetch have no cross-wave consumers at the barrier; ingest loads
// are tag-verified (consumed) before staging.
//
// WAR safety carried by tags (R19 proof): publisher X at step gt overwrites
// slot[gt&1] = h(gt-2); X's waves have tag-verified h(gt-1) from ALL 32
// blocks, and each block's h(gt-1) publish is data-dependent on its
// complete reads of h(gt-2). All cross-block traffic system-scope (L3) —
// the only scope with verifiable progress here (R13/R14 lesson).
// ---------------------------------------------------------------------------
__global__ __launch_bounds__(512, 1) void lstm_rec(
    const float* __restrict__ W,
    const float* __restrict__ h_init,
    const float* __restrict__ xw,
    float* __restrict__ out,
    float* __restrict__ c_ws,
    unsigned long long* hx,
    int t0, int nT)
{
    __shared__ float4 wlds[128][64];    // [k>>2][col_local] = w[4k..4k+3][col]
    __shared__ float4 hb4[512];         // [k] = {h_b0,h_b1,h_b2,h_b3}; [w*64..] wave-local
    __shared__ float  red[2][8][4][64]; // [parity][kslice-wave][batch][lane]

    const int tid  = threadIdx.x;
    const int p    = blockIdx.x & 7;
    const int q    = blockIdx.x >> 3;
    const int w    = tid >> 6;          // wave id = K-slice; w<4 also = batch owner
    const int lane = tid & 63;
    const int gi   = lane >> 4;
    const int u    = lane & 15;
    const int col  = gi * HH + q * 16 + u;   // this lane's global gate column

    // One-time: stage this block's recurrent W slice into LDS, k-packed.
    {
        const int cc = tid & 63;
        const int kq = tid >> 6;
        const int cg = (cc >> 4) * HH + q * 16 + (cc & 15);  // global col of cc
        const float* Wr = W + (size_t)DD * G4H + cg;
        #pragma unroll 4
        for (int i = 0; i < 16; ++i) {
            const int k4 = i * 8 + kq;          // 0..127
            float4 v;
            v.x = Wr[(size_t)(4 * k4 + 0) * G4H];
            v.y = Wr[(size_t)(4 * k4 + 1) * G4H];
            v.z = Wr[(size_t)(4 * k4 + 2) * G4H];
            v.w = Wr[(size_t)(4 * k4 + 3) * G4H];
            wlds[k4][cc] = v;
        }
    }
    __syncthreads();

    // c state: lanes 0..15 of waves 0-3 hold c[batch 4p+w][unit q*16+lane]
    float c = 0.f;
    if (t0 > 0 && w < 4 && lane < 16)
        c = c_ws[(size_t)(4 * p + w) * HH + q * 16 + lane];

    const int hoff = w * 64 + lane;       // this lane's h element (k-slice)

    // Prologue: load xw for step 0 (batch-owner waves only).
    float xg = 0.f;
    if (w < 4)
        xg = xw[((size_t)0 * BB + 4 * p + w) * G4H + col];

    for (int t = 0; t < nT; ++t) {
        const int gt = t0 + t;

        // Prefetch next step's x-part (independent; issues first).
        float xg_next = 0.f;
        if (w < 4 && t + 1 < nT)
            xg_next = xw[((size_t)(t + 1) * BB + 4 * p + w) * G4H + col];

        // 1) h ingest via tagged dataflow: 4 words/lane (one per batch).
        //    Conditional per-word reload (R16 form — only stragglers refetch).
        float h0v, h1v, h2v, h3v;
        if (gt == 0) {
            const float hv = h_init[hoff];
            h0v = hv; h1v = hv; h2v = hv; h3v = hv;
        } else {
            const unsigned int want = (unsigned int)gt;   // tag of h(gt-1)
            const unsigned long long* hs = hx + (size_t)((gt - 1) & 1) * (BB * HH);
            const unsigned long long* a0 = hs + (size_t)(4 * p + 0) * HH + hoff;
            const unsigned long long* a1 = hs + (size_t)(4 * p + 1) * HH + hoff;
            const unsigned long long* a2 = hs + (size_t)(4 * p + 2) * HH + hoff;
            const unsigned long long* a3 = hs + (size_t)(4 * p + 3) * HH + hoff;
            unsigned long long v0 = __hip_atomic_load(a0, __ATOMIC_RELAXED, __HIP_MEMORY_SCOPE_SYSTEM);
            unsigned long long v1 = __hip_atomic_load(a1, __ATOMIC_RELAXED, __HIP_MEMORY_SCOPE_SYSTEM);
            unsigned long long v2 = __hip_atomic_load(a2, __ATOMIC_RELAXED, __HIP_MEMORY_SCOPE_SYSTEM);
            unsigned long long v3 = __hip_atomic_load(a3, __ATOMIC_RELAXED, __HIP_MEMORY_SCOPE_SYSTEM);
            for (;;) {
                bool bad = false;
                if ((unsigned int)(v0 >> 32) != want) { bad = true; v0 = __hip_atomic_load(a0, __ATOMIC_RELAXED, __HIP_MEMORY_SCOPE_SYSTEM); }
                if ((unsigned int)(v1 >> 32) != want) { bad = true; v1 = __hip_atomic_load(a1, __ATOMIC_RELAXED, __HIP_MEMORY_SCOPE_SYSTEM); }
                if ((unsigned int)(v2 >> 32) != want) { bad = true; v2 = __hip_atomic_load(a2, __ATOMIC_RELAXED, __HIP_MEMORY_SCOPE_SYSTEM); }
                if ((unsigned int)(v3 >> 32) != want) { bad = true; v3 = __hip_atomic_load(a3, __ATOMIC_RELAXED, __HIP_MEMORY_SCOPE_SYSTEM); }
                if (!bad) break;
            }
            h0v = __uint_as_float((unsigned int)v0);
            h1v = __uint_as_float((unsigned int)v1);
            h2v = __uint_as_float((unsigned int)v2);
            h3v = __uint_as_float((unsigned int)v3);
        }

        // 2) Wave-local stage: ONE ds_write_b128 (unit-major, 4 batches).
        float4 hv4; hv4.x = h0v; hv4.y = h1v; hv4.z = h2v; hv4.w = h3v;
        hb4[hoff] = hv4;
        asm volatile("s_waitcnt lgkmcnt(0)" ::: "memory");
        __builtin_amdgcn_sched_barrier(0);

        // 3) K-slice dot: 16 per-lane wlds b128 + 4 broadcast b128 per j,
        //    256 FMA per lane. hb4 row r = {h_b0..h_b3} at k=r.
        const int base = w * 16;
        float a0 = 0.f, a1 = 0.f, a2 = 0.f, a3 = 0.f;
        #pragma unroll
        for (int j = 0; j < 16; ++j) {
            const float4 wv = wlds[base + j][lane];
            const float4 r0 = hb4[w * 64 + 4 * j + 0];
            const float4 r1 = hb4[w * 64 + 4 * j + 1];
            const float4 r2 = hb4[w * 64 + 4 * j + 2];
            const float4 r3 = hb4[w * 64 + 4 * j + 3];
            a0 += wv.x*r0.x; a1 += wv.x*r0.y; a2 += wv.x*r0.z; a3 += wv.x*r0.w;
            a0 += wv.y*r1.x; a1 += wv.y*r1.y; a2 += wv.y*r1.z; a3 += wv.y*r1.w;
            a0 += wv.z*r2.x; a1 += wv.z*r2.y; a2 += wv.z*r2.z; a3 += wv.z*r2.w;
            a0 += wv.w*r3.x; a1 += wv.w*r3.y; a2 += wv.w*r3.z; a3 += wv.w*r3.w;
        }

        // 4) Cross-wave reduce through parity-double-buffered red[].
        const int par = gt & 1;
        red[par][w][0][lane] = a0; red[par][w][1][lane] = a1;
        red[par][w][2][lane] = a2; red[par][w][3][lane] = a3;
        // Targeted join: drain ONLY this wave's LDS writes, raw barrier,
        // and fence compiler motion. Global ops (xg prefetch, out/hx
        // stores) stay in flight — no vmcnt(0) drain (vs __syncthreads).
        asm volatile("s_waitcnt lgkmcnt(0)" ::: "memory");
        __builtin_amdgcn_s_barrier();
        __builtin_amdgcn_sched_barrier(0);

        if (w < 4) {
            float g = xg;
            #pragma unroll
            for (int s = 0; s < 8; ++s) g += red[par][s][w][lane];

            // Per-lane activation BEFORE gather: lane's own gate type only.
            float act;
            if (gi == 3) act = 1.f - 2.f / (__expf(2.f * g) + 1.f);
            else         act = 1.f / (1.f + __expf(-g));

            const int ul = lane & 15;
            const float fv = __shfl(act, ul);
            const float iv = __shfl(act, ul + 16);
            const float ov = __shfl(act, ul + 32);
            const float gv = __shfl(act, ul + 48);

            if (lane < 16) {
                c = fv * c + iv * gv;
                const float tc = 1.f - 2.f / (__expf(2.f * c) + 1.f);
                const float h = ov * tc;
                // Tagged publish: value+tag in one 8B relaxed system store.
                // WAR safety is carried by the tags (see header comment).
                const unsigned long long pk =
                    ((unsigned long long)(unsigned int)(gt + 1) << 32) |
                    (unsigned long long)__float_as_uint(h);
                __hip_atomic_store(
                    hx + (size_t)(gt & 1) * (BB * HH) + (size_t)(4 * p + w) * HH + q * 16 + lane,
                    pk, __ATOMIC_RELAXED, __HIP_MEMORY_SCOPE_SYSTEM);
                // Output store: not read in-kernel, off the sync path.
                out[((size_t)(4 * p + w) * TT + gt) * HH + q * 16 + lane] = h;
            }
        }

        xg = xg_next;
    }

    // Spill c state for the next chunk (kernel boundary = coherence).
    if (w < 4 && lane < 16)
        c_ws[(size_t)(4 * p + w) * HH + q * 16 + lane] = c;
}

// ---------------------------------------------------------------------------
extern "C" void kernel_launch(void* const* d_in, const int* in_sizes, int n_in,
                              void* d_out, int out_size, void* d_ws, size_t ws_size,
                              hipStream_t stream) {
    const float* x      = (const float*)d_in[0];
    // d_in[1] = input_paddings (unused)
    const float* W      = (const float*)d_in[2];
    const float* bias   = (const float*)d_in[3];
    const float* h_init = (const float*)d_in[4];
    float* out = (float*)d_out;

    // ws layout: xw (CT*32*2048*4 B) | c_ws (64 KB) | hx (256 KB)
    static const int cand[] = {2048, 1024, 512, 256, 128, 64, 32, 16, 8, 4};
    const size_t extra = 65536 + 262144;
    int CT = 4;
    for (int i = 0; i < 10; ++i) {
        if ((size_t)cand[i] * BB * G4H * 4 + extra <= ws_size) { CT = cand[i]; break; }
    }
    const size_t xw_bytes = (size_t)CT * BB * G4H * 4;
    float*              xw   = (float*)d_ws;
    float*              c_ws = (float*)((char*)d_ws + xw_bytes);
    unsigned long long* hx   = (unsigned long long*)((char*)d_ws + xw_bytes + 65536);

    for (int t0 = 0; t0 < TT; t0 += CT) {
        dim3 g(G4H / 128, CT * BB / 128);
        gemm_xw<<<g, 256, 0, stream>>>(x, W, bias, xw, t0, hx);
        lstm_rec<<<256, 512, 0, stream>>>(W, h_init, xw, out, c_ws, hx, t0, CT);
    }
}